// Round 15
// baseline (208.626 us; speedup 1.0000x reference)
//
#include <hip/hip_runtime.h>
#include <hip/hip_bf16.h>
#include <stdint.h>

typedef __bf16 bf16;
typedef __bf16 bf16x8 __attribute__((ext_vector_type(8)));
typedef short s16x4 __attribute__((ext_vector_type(4)));
typedef float f32x4 __attribute__((ext_vector_type(4)));

#define DEVI __device__ __forceinline__

static constexpr int QREL_ST = 80;          // global Qrel stride (padded 65)
static constexpr float SCL2 = 0.1803368801111244f;  // 0.125 * log2(e)

DEVI void gload_lds16(const void* g, void* l) {
  __builtin_amdgcn_global_load_lds(
      (const __attribute__((address_space(1))) void*)g,
      (__attribute__((address_space(3))) void*)l, 16, 0, 0);
}

// ---------------- f32 -> bf16 convert ----------------
__global__ __launch_bounds__(256) void k_cvt(const float* __restrict__ s,
                                             bf16* __restrict__ d, int n4) {
  int i = blockIdx.x * 256 + threadIdx.x;
  if (i >= n4) return;
  float4 v = ((const float4*)s)[i];
  union { bf16 b[4]; ushort4 u; } pk;
  pk.b[0] = (bf16)v.x; pk.b[1] = (bf16)v.y;
  pk.b[2] = (bf16)v.z; pk.b[3] = (bf16)v.w;
  ((ushort4*)d)[i] = pk.u;
}

// 4 weight matrices in one launch
__global__ __launch_bounds__(256) void k_cvtw(const float* __restrict__ a,
                                              const float* __restrict__ b,
                                              const float* __restrict__ c,
                                              const float* __restrict__ e,
                                              bf16* __restrict__ d) {
  int z = blockIdx.y;
  const float* s = (z == 0) ? a : (z == 1) ? b : (z == 2) ? c : e;
  int i = blockIdx.x * 256 + threadIdx.x;
  float4 v = ((const float4*)s)[i];
  union { bf16 bb[4]; ushort4 u; } pk;
  pk.bb[0] = (bf16)v.x; pk.bb[1] = (bf16)v.y;
  pk.bb[2] = (bf16)v.z; pk.bb[3] = (bf16)v.w;
  ((ushort4*)(d + (size_t)z * 1048576))[i] = pk.u;
}

// ---------------- 128x128 bf16 MFMA GEMM, C[m,n] = sum_k A[m,k] W[n,k] -------
// MODE 0: bf16 out, head-split [bh][s][64]; MODE 1: f32 out + bias;
// MODE 2: bf16 out, head-split TRANSPOSED [bh][64][s] (Vt direct).
template <int MODE>
DEVI void gemm_core(const bf16* __restrict__ A, const bf16* __restrict__ W,
                    const float* __restrict__ bo, bf16* __restrict__ OutB,
                    float* __restrict__ OutF, int m0, int n0) {
  const int tid = threadIdx.x, wid = tid >> 6, lane = tid & 63;
  const int wr = wid >> 1, wc = wid & 1;
  __shared__ __attribute__((aligned(16))) bf16 As[128 * 32];
  __shared__ __attribute__((aligned(16))) bf16 Bs[128 * 32];
  f32x4 acc[4][4] = {};
  const int lrow = lane >> 2, lcol = (lane & 3) * 8;
  for (int k0 = 0; k0 < 1024; k0 += 32) {
    for (int c = wid; c < 8; c += 4) {
      gload_lds16(&A[(size_t)(m0 + c * 16 + lrow) * 1024 + k0 + lcol], &As[c * 512]);
      gload_lds16(&W[(size_t)(n0 + c * 16 + lrow) * 1024 + k0 + lcol], &Bs[c * 512]);
    }
    __syncthreads();
    bf16x8 af[4], bw[4];
#pragma unroll
    for (int f = 0; f < 4; ++f) {
      af[f] = *(const bf16x8*)&As[(wr * 64 + f * 16 + (lane & 15)) * 32 + (lane >> 4) * 8];
      bw[f] = *(const bf16x8*)&Bs[(wc * 64 + f * 16 + (lane & 15)) * 32 + (lane >> 4) * 8];
    }
#pragma unroll
    for (int fm = 0; fm < 4; ++fm)
#pragma unroll
      for (int fn = 0; fn < 4; ++fn)
        acc[fm][fn] = __builtin_amdgcn_mfma_f32_16x16x32_bf16(af[fm], bw[fn], acc[fm][fn], 0, 0, 0);
    __syncthreads();
  }
#pragma unroll
  for (int fm = 0; fm < 4; ++fm)
#pragma unroll
    for (int fn = 0; fn < 4; ++fn) {
      if (MODE == 2) {
        const int mb = m0 + wr * 64 + fm * 16 + (lane >> 4) * 4;
        const int n = n0 + wc * 64 + fn * 16 + (lane & 15);
        const int bh = (mb >> 10) * 16 + (n >> 6);
        union { bf16 b[4]; ushort4 u; } pk;
#pragma unroll
        for (int r = 0; r < 4; ++r) pk.b[r] = (bf16)acc[fm][fn][r];
        *(ushort4*)&OutB[((size_t)bh * 64 + (n & 63)) * 1024 + (mb & 1023)] = pk.u;
      } else {
#pragma unroll
        for (int r = 0; r < 4; ++r) {
          int m = m0 + wr * 64 + fm * 16 + (lane >> 4) * 4 + r;
          int n = n0 + wc * 64 + fn * 16 + (lane & 15);
          if (MODE == 0) {
            size_t o = ((size_t)((m >> 10) * 16 + (n >> 6)) * 1024 + (m & 1023)) * 64 + (n & 63);
            OutB[o] = (bf16)acc[fm][fn][r];
          } else {
            OutF[(size_t)m * 1024 + n] = acc[fm][fn][r] + bo[n];
          }
        }
      }
    }
}

__global__ __launch_bounds__(256) void k_gemm_qk(const bf16* __restrict__ A,
                                                 const bf16* __restrict__ Wb,
                                                 bf16* __restrict__ Qb,
                                                 bf16* __restrict__ Kb) {
  const int z = blockIdx.z;
  const bf16* W = Wb + (size_t)z * 1024 * 1024;
  bf16* Out = (z == 0) ? Qb : Kb;
  gemm_core<0>(A, W, nullptr, Out, nullptr, blockIdx.x * 128, blockIdx.y * 128);
}

// V projection written DIRECTLY transposed to Vt [bh][64][s]
__global__ __launch_bounds__(256) void k_gemm_v(const bf16* __restrict__ A,
                                                const bf16* __restrict__ Wv,
                                                bf16* __restrict__ Vt) {
  gemm_core<2>(A, Wv, nullptr, Vt, nullptr, blockIdx.x * 128, blockIdx.y * 128);
}

__global__ __launch_bounds__(256) void k_gemm_out(const bf16* __restrict__ A,
                                                  const bf16* __restrict__ W,
                                                  const float* __restrict__ bo,
                                                  float* __restrict__ Out) {
  gemm_core<1>(A, W, bo, nullptr, Out, blockIdx.x * 128, blockIdx.y * 128);
}

// -------- Qrel[i, r] = (Q_i . rel_k[r]) * 0.125*log2(e)  (bf16, stride 80) --
__global__ __launch_bounds__(256) void k_qrel(const bf16* __restrict__ Qb,
                                              const float* __restrict__ relk,
                                              bf16* __restrict__ Qrel) {
  const int m0 = blockIdx.x * 64;
  const int tid = threadIdx.x, wid = tid >> 6, lane = tid & 63;
  __shared__ __attribute__((aligned(16))) bf16 RK[80 * 72];
  for (int i = tid; i < 80 * 72; i += 256) {
    int r = i / 72, dd = i % 72;
    RK[i] = (r < 65 && dd < 64) ? (bf16)relk[r * 64 + dd] : (bf16)0.0f;
  }
  __syncthreads();
  bf16x8 qa[2];
#pragma unroll
  for (int kk = 0; kk < 2; ++kk)
    qa[kk] = *(const bf16x8*)&Qb[(size_t)(m0 + wid * 16 + (lane & 15)) * 64 + kk * 32 + (lane >> 4) * 8];
  f32x4 acc[5] = {};
#pragma unroll
  for (int fc = 0; fc < 5; ++fc)
#pragma unroll
    for (int kk = 0; kk < 2; ++kk) {
      bf16x8 rb = *(const bf16x8*)&RK[(fc * 16 + (lane & 15)) * 72 + kk * 32 + (lane >> 4) * 8];
      acc[fc] = __builtin_amdgcn_mfma_f32_16x16x32_bf16(qa[kk], rb, acc[fc], 0, 0, 0);
    }
#pragma unroll
  for (int fc = 0; fc < 5; ++fc)
#pragma unroll
    for (int r = 0; r < 4; ++r)
      Qrel[(size_t)(m0 + wid * 16 + (lane >> 4) * 4 + r) * QREL_ST + fc * 16 + (lane & 15)] =
          (bf16)(acc[fc][r] * SCL2);
}

// -------- rel_v^T prep: RVt[d*96 + r] = relv[r][d], zero-padded to 96 -------
__global__ __launch_bounds__(256) void k_prep(const float* __restrict__ relv,
                                              bf16* __restrict__ RVt) {
  int i = blockIdx.x * 256 + threadIdx.x;
  if (i >= 64 * 96) return;
  int d = i / 96, r = i % 96;
  RVt[i] = (r < 65) ? (bf16)relv[r * 64 + d] : (bf16)0.0f;
}

// ---------------- fused attention ----------------
// EXACT R9 structure (84us, twice-verified): single-buffer KS/VS, STAGE
// issued between the two barriers per tile (proven-safe drain pattern),
// 33.8KB LDS -> 4 blocks/CU, hoisted LDS/global pointers, setprio on MFMA.
__global__ __launch_bounds__(256, 4) void k_attn(const bf16* __restrict__ Qb,
                                                 const bf16* __restrict__ Kb,
                                                 const bf16* __restrict__ Vt,
                                                 const bf16* __restrict__ Qrel,
                                                 const bf16* __restrict__ RVt,
                                                 const float* __restrict__ relv,
                                                 bf16* __restrict__ Ctx) {
  const int jb = blockIdx.x;
  const int xcd = jb & 7, rlin = jb >> 3;
  const int bh = xcd + 8 * (rlin >> 4);   // XCD-affinity, bijective
  const int tq = rlin & 15, q0 = tq * 64;
  const int tid = threadIdx.x, wid = tid >> 6, lane = tid & 63;
  __shared__ __attribute__((aligned(16))) bf16 Qrl[64 * 72];   // 9216 B
  __shared__ __attribute__((aligned(16))) bf16 KS[64 * 64];    // 8192 B
  __shared__ __attribute__((aligned(16))) bf16 VS[64 * 64];    // 8192 B
  __shared__ __attribute__((aligned(16))) bf16 BUK[64 * 64];   // 8192 B

  // stage Qrel rows (global stride 80 -> LDS stride 72) + zero BUK
  for (int i = tid; i < 576; i += 256) {
    int row = i / 9, u4 = (i % 9) * 8;
    *(uint4*)&Qrl[row * 72 + u4] =
        *(const uint4*)&Qrel[((size_t)bh * 1024 + q0 + row) * QREL_ST + u4];
  }
  {
    uint4 z4 = {0, 0, 0, 0};
    uint4* bz = (uint4*)BUK;
    for (int i = tid; i < 512; i += 256) bz[i] = z4;
  }

  const int q16 = lane & 15, lhi = lane >> 4;
  const int qrow = wid * 16 + q16;
  const int qglob = q0 + qrow;
  const size_t kvb = (size_t)bh * 65536;

  // staging geometry: per wave 2 chunks x (K,V); chunk = 8 rows x 128B.
  // LDS dest linear; global source column pre-swizzled (guide #21).
  const int srow = lane >> 3;                      // row within chunk (0..7)
  const int scol = (((lane & 7) ^ srow)) * 8;      // swizzled elem col

  // hoisted global staging pointers (advance by induction each tile)
  const bf16* kg0 = Kb + kvb + (size_t)((wid * 2 + 0) * 8 + srow) * 64 + scol;
  const bf16* kg1 = Kb + kvb + (size_t)((wid * 2 + 1) * 8 + srow) * 64 + scol;
  const bf16* vg0 = Vt + kvb + (size_t)((wid * 2 + 0) * 8 + srow) * 1024 + scol;
  const bf16* vg1 = Vt + kvb + (size_t)((wid * 2 + 1) * 8 + srow) * 1024 + scol;
  bf16* kd0 = &KS[(wid * 2 + 0) * 512];
  bf16* kd1 = &KS[(wid * 2 + 1) * 512];
  bf16* vd0 = &VS[(wid * 2 + 0) * 512];
  bf16* vd1 = &VS[(wid * 2 + 1) * 512];

#define STAGE_ISSUE()                                                          \
  do {                                                                         \
    gload_lds16(kg0, kd0); gload_lds16(kg1, kd1);                              \
    gload_lds16(vg0, vd0); gload_lds16(vg1, vd1);                              \
    kg0 += 4096; kg1 += 4096; vg0 += 64; vg1 += 64;                            \
  } while (0)

  bf16x8 qa[2];  // Q as B-operand (R5-verified)
#pragma unroll
  for (int kk = 0; kk < 2; ++kk)
    qa[kk] = *(const bf16x8*)&Qb[kvb + (size_t)qglob * 64 + kk * 32 + lhi * 8];

  f32x4 o[4] = {};
  float rowsum = 0.f, sumL = 0.f, sumR = 0.f;

  union PU { bf16 b[4]; s16x4 s; };
  union VU { uint2 u; s16x4 s; };

  STAGE_ISSUE();
  __syncthreads();      // Qrl/BUK + first stage visible
  const float biasL = (float)Qrl[qrow * 72 + 0];
  const float biasR = (float)Qrl[qrow * 72 + 64];

  const int swz = (q16 & 7) * 8;
  // hoisted LDS read base pointers (loop-invariant; inner reads use imm offs)
  const bf16* kp0 = &KS[q16 * 64 + ((lhi * 8) ^ swz)];
  const bf16* kp1 = &KS[q16 * 64 + ((32 + lhi * 8) ^ swz)];
  const bf16* vp[4] = {
      &VS[q16 * 64 + ((0 * 16 + lhi * 4) ^ swz)],
      &VS[q16 * 64 + ((1 * 16 + lhi * 4) ^ swz)],
      &VS[q16 * 64 + ((2 * 16 + lhi * 4) ^ swz)],
      &VS[q16 * 64 + ((3 * 16 + lhi * 4) ^ swz)]};
  const bf16* qrp = &Qrl[qrow * 72 + 32];   // band bias gather base
  bf16* bkp = &BUK[qrow * 64 + 32];         // band bucket write base

  for (int t = 0; t < 16; ++t) {
    const int kv0 = t * 64;
    const int kind = (t <= tq - 2) ? 0 : (t >= tq + 2) ? 1 : 2;
    // ---- S^T = K . Q^T from LDS ----
    f32x4 st[4] = {};
    __builtin_amdgcn_s_setprio(1);
#pragma unroll
    for (int jt = 0; jt < 4; ++jt) {
      bf16x8 k0 = *(const bf16x8*)(kp0 + jt * 1024);
      bf16x8 k1 = *(const bf16x8*)(kp1 + jt * 1024);
      st[jt] = __builtin_amdgcn_mfma_f32_16x16x32_bf16(k0, qa[0], st[jt], 0, 0, 0);
      st[jt] = __builtin_amdgcn_mfma_f32_16x16x32_bf16(k1, qa[1], st[jt], 0, 0, 0);
    }
    __builtin_amdgcn_s_setprio(0);
    // ---- exp + buckets, P packed in registers ----
    PU pk[4];
    if (kind == 0) {
#pragma unroll
      for (int jt = 0; jt < 4; ++jt)
#pragma unroll
        for (int r = 0; r < 4; ++r) {
          float p = __builtin_amdgcn_exp2f(__builtin_fmaf(st[jt][r], SCL2, biasL));
          rowsum += p; sumL += p;
          pk[jt].b[r] = (bf16)p;
        }
    } else if (kind == 1) {
#pragma unroll
      for (int jt = 0; jt < 4; ++jt)
#pragma unroll
        for (int r = 0; r < 4; ++r) {
          float p = __builtin_amdgcn_exp2f(__builtin_fmaf(st[jt][r], SCL2, biasR));
          rowsum += p; sumR += p;
          pk[jt].b[r] = (bf16)p;
        }
    } else {
#pragma unroll
      for (int jt = 0; jt < 4; ++jt)
#pragma unroll
        for (int r = 0; r < 4; ++r) {
          const int j = kv0 + jt * 16 + lhi * 4 + r;
          const int delta = j - qglob;
          const int dc = delta < -32 ? -32 : (delta > 32 ? 32 : delta);
          const float b = (float)qrp[dc];
          float p = __builtin_amdgcn_exp2f(__builtin_fmaf(st[jt][r], SCL2, b));
          rowsum += p;
          pk[jt].b[r] = (bf16)p;
          if (delta <= -32) sumL += p;
          else if (delta >= 32) sumR += p;
          else bkp[delta] = (bf16)p;  // unique (q,delta) per lane
        }
    }
    // ---- PV from LDS V^T ----
    __builtin_amdgcn_s_setprio(1);
#pragma unroll
    for (int jt = 0; jt < 4; ++jt)
#pragma unroll
      for (int fd = 0; fd < 4; ++fd) {
        VU v;
        v.u = *(const uint2*)(vp[jt] + fd * 1024);
        o[fd] = __builtin_amdgcn_mfma_f32_16x16x16bf16_1k(pk[jt].s, v.s, o[fd], 0, 0, 0);
      }
    __builtin_amdgcn_s_setprio(0);
    __syncthreads();      // all waves done reading KS/VS
    if (t < 15) {
      STAGE_ISSUE();
      __syncthreads();    // staged data visible
    }
  }
#undef STAGE_ISSUE

  // ---- reduce row stats over the 4 lanes sharing q ----
  rowsum += __shfl_xor(rowsum, 16, 64);
  rowsum += __shfl_xor(rowsum, 32, 64);
  sumL += __shfl_xor(sumL, 16, 64);
  sumL += __shfl_xor(sumL, 32, 64);
  sumR += __shfl_xor(sumR, 16, 64);
  sumR += __shfl_xor(sumR, 32, 64);
  if (lhi == 0) BUK[qrow * 64 + 0] = (bf16)sumL;   // bucket 0

  float linv[4], sumRr[4];
#pragma unroll
  for (int r = 0; r < 4; ++r) {
    linv[r] = 1.0f / __shfl(rowsum, lhi * 4 + r, 16);
    sumRr[r] = __shfl(sumR, lhi * 4 + r, 16);
  }

  // ---- bucket-sums (0..63) @ rel_v ; rel_v frags straight from global ----
#pragma unroll
  for (int kk = 0; kk < 2; ++kk) {
    bf16x8 pa = *(const bf16x8*)&BUK[(wid * 16 + q16) * 64 + kk * 32 + lhi * 8];
#pragma unroll
    for (int fd = 0; fd < 4; ++fd) {
      bf16x8 rb = *(const bf16x8*)&RVt[(fd * 16 + q16) * 96 + kk * 32 + lhi * 8];
      o[fd] = __builtin_amdgcn_mfma_f32_16x16x32_bf16(pa, rb, o[fd], 0, 0, 0);
    }
  }
  // ---- bucket 64 rank-1 update: o[q][d] += sumR[q] * relv[64][d] ----
#pragma unroll
  for (int fd = 0; fd < 4; ++fd) {
    float rv64 = relv[64 * 64 + fd * 16 + q16];
#pragma unroll
    for (int r = 0; r < 4; ++r) o[fd][r] += sumRr[r] * rv64;
  }

  // ---- scale + stage output rows (overlay on Qrl, stride 72) ----
  const int rbase = wid * 16 + lhi * 4;
  __syncthreads();  // Qrl bias/band reads all done; reuse as OL
  bf16* OL = Qrl;
#pragma unroll
  for (int fd = 0; fd < 4; ++fd)
#pragma unroll
    for (int r = 0; r < 4; ++r)
      OL[(rbase + r) * 72 + fd * 16 + q16] = (bf16)(o[fd][r] * linv[r]);
  __syncthreads();
  {  // coalesced ctx write back to [b][s][h*64+d]
    int il = tid >> 2, d0 = (tid & 3) * 16;
    union { bf16 b[16]; uint4 u[2]; } pkk;
#pragma unroll
    for (int c = 0; c < 16; ++c) pkk.b[c] = OL[il * 72 + d0 + c];
    size_t base = ((size_t)(bh >> 4) * 1024 + q0 + il) * 1024 + (bh & 15) * 64 + d0;
    *(uint4*)&Ctx[base] = pkk.u[0];
    *(uint4*)&Ctx[base + 8] = pkk.u[1];
  }
}

// ---------------- launch ----------------
extern "C" void kernel_launch(void* const* d_in, const int* in_sizes, int n_in,
                              void* d_out, int out_size, void* d_ws, size_t ws_size,
                              hipStream_t stream) {
  const float* x = (const float*)d_in[0];
  const float* Wq = (const float*)d_in[1];
  const float* Wk = (const float*)d_in[2];
  const float* Wv = (const float*)d_in[3];
  const float* Wo = (const float*)d_in[4];
  const float* bo = (const float*)d_in[5];
  const float* relk = (const float*)d_in[6];
  const float* relv = (const float*)d_in[7];
  float* out = (float*)d_out;

  uint8_t* w = (uint8_t*)d_ws;
  bf16* xb = (bf16*)(w);                          // 16 MB  [8192][1024]
  bf16* Wb = (bf16*)(w + 16777216);               // 8 MB   [4][1024][1024]
  bf16* Qb = (bf16*)(w + 25165824);               // 16 MB  [bh][s][64]
  bf16* Kb = (bf16*)(w + 41943040);               // 16 MB
  bf16* Vb = (bf16*)(w + 58720256);               // 16 MB  (spare -> Ctx)
  bf16* Vt = (bf16*)(w + 75497472);               // 16 MB  [bh][64][s]
  bf16* Qrel = (bf16*)(w + 92274688);             // 21 MB  [bh*s][80]
  bf16* Ctx = Vb;                                 // overlay (spare region)
  bf16* RVt = xb;                                 // overlay (xb dead after gemms)

  k_cvt<<<8192, 256, 0, stream>>>(x, xb, 2097152);
  k_cvtw<<<dim3(1024, 4), 256, 0, stream>>>(Wq, Wk, Wv, Wo, Wb);

  k_gemm_qk<<<dim3(64, 8, 2), 256, 0, stream>>>(xb, Wb, Qb, Kb);
  k_gemm_v<<<dim3(64, 8), 256, 0, stream>>>(xb, Wb + 2 * 1048576, Vt);
  k_qrel<<<2048, 256, 0, stream>>>(Qb, relk, Qrel);
  k_prep<<<24, 256, 0, stream>>>(relv, RVt);
  k_attn<<<2048, 256, 0, stream>>>(Qb, Kb, Vt, Qrel, RVt, relv, Ctx);
  k_gemm_out<<<dim3(64, 8), 256, 0, stream>>>(Ctx, Wb + 3 * 1048576, bo, out);
}

// Round 16
// 186.312 us; speedup vs baseline: 1.1198x; 1.1198x over previous
//
#include <hip/hip_runtime.h>
#include <hip/hip_bf16.h>
#include <stdint.h>

typedef __bf16 bf16;
typedef __bf16 bf16x8 __attribute__((ext_vector_type(8)));
typedef short s16x4 __attribute__((ext_vector_type(4)));
typedef float f32x4 __attribute__((ext_vector_type(4)));

#define DEVI __device__ __forceinline__

static constexpr int QREL_ST = 80;          // global Qrel stride (padded 65)
static constexpr float SCL2 = 0.1803368801111244f;  // 0.125 * log2(e)

DEVI void gload_lds16(const void* g, void* l) {
  __builtin_amdgcn_global_load_lds(
      (const __attribute__((address_space(1))) void*)g,
      (__attribute__((address_space(3))) void*)l, 16, 0, 0);
}

// ------- fused f32->bf16 convert: x (8192 blocks) + 4 weights (4096) -------
__global__ __launch_bounds__(256) void k_cvtall(const float* __restrict__ x,
                                                const float* __restrict__ a,
                                                const float* __restrict__ b,
                                                const float* __restrict__ c,
                                                const float* __restrict__ e,
                                                bf16* __restrict__ xb,
                                                bf16* __restrict__ Wb) {
  const int blk = blockIdx.x, tid = threadIdx.x;
  const float* s;
  ushort4* dst;
  int i;
  if (blk < 8192) {            // x: 2097152 float4
    i = blk * 256 + tid;
    s = x;
    dst = (ushort4*)xb;
  } else {                     // weights: 1048576 float4 (4 x 262144)
    i = (blk - 8192) * 256 + tid;
    const int z = i >> 18;     // / 262144
    const float* ws[4] = {a, b, c, e};
    s = ws[z] - (size_t)z * 1048576;  // so s + 4*i indexes within the right W
    dst = (ushort4*)Wb;
  }
  float4 v = ((const float4*)s)[i];
  union { bf16 bb[4]; ushort4 u; } pk;
  pk.bb[0] = (bf16)v.x; pk.bb[1] = (bf16)v.y;
  pk.bb[2] = (bf16)v.z; pk.bb[3] = (bf16)v.w;
  dst[i] = pk.u;
}

// ------- 128x128 bf16 MFMA GEMM, BK=64 (two 128x32 sub-tiles / barrier) ----
// MODE 0: bf16 out, head-split [bh][s][64]; MODE 1: f32 out + bias.
template <int MODE>
DEVI void gemm_core(const bf16* __restrict__ A, const bf16* __restrict__ W,
                    const float* __restrict__ bo, bf16* __restrict__ OutB,
                    float* __restrict__ OutF, int m0, int n0) {
  const int tid = threadIdx.x, wid = tid >> 6, lane = tid & 63;
  const int wr = wid >> 1, wc = wid & 1;
  __shared__ __attribute__((aligned(16))) bf16 As[2][128 * 32];
  __shared__ __attribute__((aligned(16))) bf16 Bs[2][128 * 32];
  f32x4 acc[4][4] = {};
  const int lrow = lane >> 2, lcol = (lane & 3) * 8;
  for (int k0 = 0; k0 < 1024; k0 += 64) {
    for (int c = wid; c < 8; c += 4) {
      const size_t ra = (size_t)(m0 + c * 16 + lrow) * 1024 + k0 + lcol;
      const size_t rb = (size_t)(n0 + c * 16 + lrow) * 1024 + k0 + lcol;
      gload_lds16(&A[ra], &As[0][c * 512]);
      gload_lds16(&A[ra + 32], &As[1][c * 512]);
      gload_lds16(&W[rb], &Bs[0][c * 512]);
      gload_lds16(&W[rb + 32], &Bs[1][c * 512]);
    }
    __syncthreads();
#pragma unroll
    for (int s = 0; s < 2; ++s) {
      bf16x8 af[4], bw[4];
#pragma unroll
      for (int f = 0; f < 4; ++f) {
        af[f] = *(const bf16x8*)&As[s][(wr * 64 + f * 16 + (lane & 15)) * 32 + (lane >> 4) * 8];
        bw[f] = *(const bf16x8*)&Bs[s][(wc * 64 + f * 16 + (lane & 15)) * 32 + (lane >> 4) * 8];
      }
#pragma unroll
      for (int fm = 0; fm < 4; ++fm)
#pragma unroll
        for (int fn = 0; fn < 4; ++fn)
          acc[fm][fn] = __builtin_amdgcn_mfma_f32_16x16x32_bf16(af[fm], bw[fn], acc[fm][fn], 0, 0, 0);
    }
    __syncthreads();
  }
#pragma unroll
  for (int fm = 0; fm < 4; ++fm)
#pragma unroll
    for (int fn = 0; fn < 4; ++fn)
#pragma unroll
      for (int r = 0; r < 4; ++r) {
        int m = m0 + wr * 64 + fm * 16 + (lane >> 4) * 4 + r;
        int n = n0 + wc * 64 + fn * 16 + (lane & 15);
        if (MODE == 0) {
          size_t o = ((size_t)((m >> 10) * 16 + (n >> 6)) * 1024 + (m & 1023)) * 64 + (n & 63);
          OutB[o] = (bf16)acc[fm][fn][r];
        } else {
          OutF[(size_t)m * 1024 + n] = acc[fm][fn][r] + bo[n];
        }
      }
}

__global__ __launch_bounds__(256) void k_gemm_qkv(const bf16* __restrict__ A,
                                                  const bf16* __restrict__ Wb,
                                                  bf16* __restrict__ Qb,
                                                  bf16* __restrict__ Kb,
                                                  bf16* __restrict__ Vb) {
  const int z = blockIdx.z;
  const bf16* W = Wb + (size_t)z * 1024 * 1024;
  bf16* Out = (z == 0) ? Qb : ((z == 1) ? Kb : Vb);
  gemm_core<0>(A, W, nullptr, Out, nullptr, blockIdx.x * 128, blockIdx.y * 128);
}

__global__ __launch_bounds__(256) void k_gemm_out(const bf16* __restrict__ A,
                                                  const bf16* __restrict__ W,
                                                  const float* __restrict__ bo,
                                                  float* __restrict__ Out) {
  gemm_core<1>(A, W, bo, nullptr, Out, blockIdx.x * 128, blockIdx.y * 128);
}

// ---------------- V transpose: [bh][s][64] -> [bh][64][s] ----------------
__global__ __launch_bounds__(256) void k_transpose(const bf16* __restrict__ Vb,
                                                   bf16* __restrict__ Vt) {
  const int s0 = blockIdx.x * 64, bh = blockIdx.y;
  __shared__ __attribute__((aligned(16))) bf16 T[64 * 72];
  const int tid = threadIdx.x;
#pragma unroll
  for (int c = 0; c < 2; ++c) {
    int flat = c * 256 + tid;
    int row = flat >> 3, c8 = (flat & 7) * 8;
    *(uint4*)&T[row * 72 + c8] =
        *(const uint4*)&Vb[((size_t)bh * 1024 + s0 + row) * 64 + c8];
  }
  __syncthreads();
  const int d = tid >> 2, j0 = (tid & 3) * 16;
  union { bf16 b[16]; uint4 u[2]; } pk;
#pragma unroll
  for (int j = 0; j < 16; ++j) pk.b[j] = T[(j0 + j) * 72 + d];
  size_t base = ((size_t)bh * 64 + d) * 1024 + s0 + j0;
  *(uint4*)&Vt[base] = pk.u[0];
  *(uint4*)&Vt[base + 8] = pk.u[1];
}

// ---- Qrel[i,r] = (Q_i . rel_k[r]) * 0.125*log2(e), + fused rel_v^T prep ----
__global__ __launch_bounds__(256) void k_qrel(const bf16* __restrict__ Qb,
                                              const float* __restrict__ relk,
                                              bf16* __restrict__ Qrel,
                                              const float* __restrict__ relv,
                                              bf16* __restrict__ RVt) {
  if (blockIdx.x >= 2048) {   // fused k_prep: RVt[d*96+r] = relv[r][d]
    int i = (blockIdx.x - 2048) * 256 + threadIdx.x;
    if (i < 64 * 96) {
      int d = i / 96, r = i % 96;
      RVt[i] = (r < 65) ? (bf16)relv[r * 64 + d] : (bf16)0.0f;
    }
    return;
  }
  const int m0 = blockIdx.x * 64;
  const int tid = threadIdx.x, wid = tid >> 6, lane = tid & 63;
  __shared__ __attribute__((aligned(16))) bf16 RK[80 * 72];
  for (int i = tid; i < 80 * 72; i += 256) {
    int r = i / 72, dd = i % 72;
    RK[i] = (r < 65 && dd < 64) ? (bf16)relk[r * 64 + dd] : (bf16)0.0f;
  }
  __syncthreads();
  bf16x8 qa[2];
#pragma unroll
  for (int kk = 0; kk < 2; ++kk)
    qa[kk] = *(const bf16x8*)&Qb[(size_t)(m0 + wid * 16 + (lane & 15)) * 64 + kk * 32 + (lane >> 4) * 8];
  f32x4 acc[5] = {};
#pragma unroll
  for (int fc = 0; fc < 5; ++fc)
#pragma unroll
    for (int kk = 0; kk < 2; ++kk) {
      bf16x8 rb = *(const bf16x8*)&RK[(fc * 16 + (lane & 15)) * 72 + kk * 32 + (lane >> 4) * 8];
      acc[fc] = __builtin_amdgcn_mfma_f32_16x16x32_bf16(qa[kk], rb, acc[fc], 0, 0, 0);
    }
#pragma unroll
  for (int fc = 0; fc < 5; ++fc)
#pragma unroll
    for (int r = 0; r < 4; ++r)
      Qrel[(size_t)(m0 + wid * 16 + (lane >> 4) * 4 + r) * QREL_ST + fc * 16 + (lane & 15)] =
          (bf16)(acc[fc][r] * SCL2);
}

// ---------------- fused attention (EXACT R9/R15 verified core) ----------------
__global__ __launch_bounds__(256, 4) void k_attn(const bf16* __restrict__ Qb,
                                                 const bf16* __restrict__ Kb,
                                                 const bf16* __restrict__ Vt,
                                                 const bf16* __restrict__ Qrel,
                                                 const bf16* __restrict__ RVt,
                                                 const float* __restrict__ relv,
                                                 bf16* __restrict__ Ctx) {
  const int jb = blockIdx.x;
  const int xcd = jb & 7, rlin = jb >> 3;
  const int bh = xcd + 8 * (rlin >> 4);   // XCD-affinity, bijective
  const int tq = rlin & 15, q0 = tq * 64;
  const int tid = threadIdx.x, wid = tid >> 6, lane = tid & 63;
  __shared__ __attribute__((aligned(16))) bf16 Qrl[64 * 72];   // 9216 B
  __shared__ __attribute__((aligned(16))) bf16 KS[64 * 64];    // 8192 B
  __shared__ __attribute__((aligned(16))) bf16 VS[64 * 64];    // 8192 B
  __shared__ __attribute__((aligned(16))) bf16 BUK[64 * 64];   // 8192 B

  // stage Qrel rows (global stride 80 -> LDS stride 72) + zero BUK
  for (int i = tid; i < 576; i += 256) {
    int row = i / 9, u4 = (i % 9) * 8;
    *(uint4*)&Qrl[row * 72 + u4] =
        *(const uint4*)&Qrel[((size_t)bh * 1024 + q0 + row) * QREL_ST + u4];
  }
  {
    uint4 z4 = {0, 0, 0, 0};
    uint4* bz = (uint4*)BUK;
    for (int i = tid; i < 512; i += 256) bz[i] = z4;
  }

  const int q16 = lane & 15, lhi = lane >> 4;
  const int qrow = wid * 16 + q16;
  const int qglob = q0 + qrow;
  const size_t kvb = (size_t)bh * 65536;

  const int srow = lane >> 3;                      // row within chunk (0..7)
  const int scol = (((lane & 7) ^ srow)) * 8;      // swizzled elem col

  const bf16* kg0 = Kb + kvb + (size_t)((wid * 2 + 0) * 8 + srow) * 64 + scol;
  const bf16* kg1 = Kb + kvb + (size_t)((wid * 2 + 1) * 8 + srow) * 64 + scol;
  const bf16* vg0 = Vt + kvb + (size_t)((wid * 2 + 0) * 8 + srow) * 1024 + scol;
  const bf16* vg1 = Vt + kvb + (size_t)((wid * 2 + 1) * 8 + srow) * 1024 + scol;
  bf16* kd0 = &KS[(wid * 2 + 0) * 512];
  bf16* kd1 = &KS[(wid * 2 + 1) * 512];
  bf16* vd0 = &VS[(wid * 2 + 0) * 512];
  bf16* vd1 = &VS[(wid * 2 + 1) * 512];

#define STAGE_ISSUE()                                                          \
  do {                                                                         \
    gload_lds16(kg0, kd0); gload_lds16(kg1, kd1);                              \
    gload_lds16(vg0, vd0); gload_lds16(vg1, vd1);                              \
    kg0 += 4096; kg1 += 4096; vg0 += 64; vg1 += 64;                            \
  } while (0)

  bf16x8 qa[2];  // Q as B-operand (R5-verified)
#pragma unroll
  for (int kk = 0; kk < 2; ++kk)
    qa[kk] = *(const bf16x8*)&Qb[kvb + (size_t)qglob * 64 + kk * 32 + lhi * 8];

  f32x4 o[4] = {};
  float rowsum = 0.f, sumL = 0.f, sumR = 0.f;

  union PU { bf16 b[4]; s16x4 s; };
  union VU { uint2 u; s16x4 s; };

  STAGE_ISSUE();
  __syncthreads();      // Qrl/BUK + first stage visible
  const float biasL = (float)Qrl[qrow * 72 + 0];
  const float biasR = (float)Qrl[qrow * 72 + 64];

  const int swz = (q16 & 7) * 8;
  const bf16* kp0 = &KS[q16 * 64 + ((lhi * 8) ^ swz)];
  const bf16* kp1 = &KS[q16 * 64 + ((32 + lhi * 8) ^ swz)];
  const bf16* vp[4] = {
      &VS[q16 * 64 + ((0 * 16 + lhi * 4) ^ swz)],
      &VS[q16 * 64 + ((1 * 16 + lhi * 4) ^ swz)],
      &VS[q16 * 64 + ((2 * 16 + lhi * 4) ^ swz)],
      &VS[q16 * 64 + ((3 * 16 + lhi * 4) ^ swz)]};
  const bf16* qrp = &Qrl[qrow * 72 + 32];   // band bias gather base
  bf16* bkp = &BUK[qrow * 64 + 32];         // band bucket write base

  for (int t = 0; t < 16; ++t) {
    const int kv0 = t * 64;
    const int kind = (t <= tq - 2) ? 0 : (t >= tq + 2) ? 1 : 2;
    // ---- S^T = K . Q^T from LDS ----
    f32x4 st[4] = {};
    __builtin_amdgcn_s_setprio(1);
#pragma unroll
    for (int jt = 0; jt < 4; ++jt) {
      bf16x8 k0 = *(const bf16x8*)(kp0 + jt * 1024);
      bf16x8 k1 = *(const bf16x8*)(kp1 + jt * 1024);
      st[jt] = __builtin_amdgcn_mfma_f32_16x16x32_bf16(k0, qa[0], st[jt], 0, 0, 0);
      st[jt] = __builtin_amdgcn_mfma_f32_16x16x32_bf16(k1, qa[1], st[jt], 0, 0, 0);
    }
    __builtin_amdgcn_s_setprio(0);
    // ---- exp + buckets, P packed in registers ----
    PU pk[4];
    if (kind == 0) {
#pragma unroll
      for (int jt = 0; jt < 4; ++jt)
#pragma unroll
        for (int r = 0; r < 4; ++r) {
          float p = __builtin_amdgcn_exp2f(__builtin_fmaf(st[jt][r], SCL2, biasL));
          rowsum += p; sumL += p;
          pk[jt].b[r] = (bf16)p;
        }
    } else if (kind == 1) {
#pragma unroll
      for (int jt = 0; jt < 4; ++jt)
#pragma unroll
        for (int r = 0; r < 4; ++r) {
          float p = __builtin_amdgcn_exp2f(__builtin_fmaf(st[jt][r], SCL2, biasR));
          rowsum += p; sumR += p;
          pk[jt].b[r] = (bf16)p;
        }
    } else {
#pragma unroll
      for (int jt = 0; jt < 4; ++jt)
#pragma unroll
        for (int r = 0; r < 4; ++r) {
          const int j = kv0 + jt * 16 + lhi * 4 + r;
          const int delta = j - qglob;
          const int dc = delta < -32 ? -32 : (delta > 32 ? 32 : delta);
          const float b = (float)qrp[dc];
          float p = __builtin_amdgcn_exp2f(__builtin_fmaf(st[jt][r], SCL2, b));
          rowsum += p;
          pk[jt].b[r] = (bf16)p;
          if (delta <= -32) sumL += p;
          else if (delta >= 32) sumR += p;
          else bkp[delta] = (bf16)p;  // unique (q,delta) per lane
        }
    }
    // ---- PV from LDS V^T ----
    __builtin_amdgcn_s_setprio(1);
#pragma unroll
    for (int jt = 0; jt < 4; ++jt)
#pragma unroll
      for (int fd = 0; fd < 4; ++fd) {
        VU v;
        v.u = *(const uint2*)(vp[jt] + fd * 1024);
        o[fd] = __builtin_amdgcn_mfma_f32_16x16x16bf16_1k(pk[jt].s, v.s, o[fd], 0, 0, 0);
      }
    __builtin_amdgcn_s_setprio(0);
    __syncthreads();      // all waves done reading KS/VS
    if (t < 15) {
      STAGE_ISSUE();
      __syncthreads();    // staged data visible
    }
  }
#undef STAGE_ISSUE

  // ---- reduce row stats over the 4 lanes sharing q ----
  rowsum += __shfl_xor(rowsum, 16, 64);
  rowsum += __shfl_xor(rowsum, 32, 64);
  sumL += __shfl_xor(sumL, 16, 64);
  sumL += __shfl_xor(sumL, 32, 64);
  sumR += __shfl_xor(sumR, 16, 64);
  sumR += __shfl_xor(sumR, 32, 64);
  if (lhi == 0) BUK[qrow * 64 + 0] = (bf16)sumL;   // bucket 0

  float linv[4], sumRr[4];
#pragma unroll
  for (int r = 0; r < 4; ++r) {
    linv[r] = 1.0f / __shfl(rowsum, lhi * 4 + r, 16);
    sumRr[r] = __shfl(sumR, lhi * 4 + r, 16);
  }

  // ---- bucket-sums (0..63) @ rel_v ; rel_v frags straight from global ----
#pragma unroll
  for (int kk = 0; kk < 2; ++kk) {
    bf16x8 pa = *(const bf16x8*)&BUK[(wid * 16 + q16) * 64 + kk * 32 + lhi * 8];
#pragma unroll
    for (int fd = 0; fd < 4; ++fd) {
      bf16x8 rb = *(const bf16x8*)&RVt[(fd * 16 + q16) * 96 + kk * 32 + lhi * 8];
      o[fd] = __builtin_amdgcn_mfma_f32_16x16x32_bf16(pa, rb, o[fd], 0, 0, 0);
    }
  }
  // ---- bucket 64 rank-1 update: o[q][d] += sumR[q] * relv[64][d] ----
#pragma unroll
  for (int fd = 0; fd < 4; ++fd) {
    float rv64 = relv[64 * 64 + fd * 16 + q16];
#pragma unroll
    for (int r = 0; r < 4; ++r) o[fd][r] += sumRr[r] * rv64;
  }

  // ---- scale + stage output rows (overlay on Qrl, stride 72) ----
  const int rbase = wid * 16 + lhi * 4;
  __syncthreads();  // Qrl bias/band reads all done; reuse as OL
  bf16* OL = Qrl;
#pragma unroll
  for (int fd = 0; fd < 4; ++fd)
#pragma unroll
    for (int r = 0; r < 4; ++r)
      OL[(rbase + r) * 72 + fd * 16 + q16] = (bf16)(o[fd][r] * linv[r]);
  __syncthreads();
  {  // coalesced ctx write back to [b][s][h*64+d]
    int il = tid >> 2, d0 = (tid & 3) * 16;
    union { bf16 b[16]; uint4 u[2]; } pkk;
#pragma unroll
    for (int c = 0; c < 16; ++c) pkk.b[c] = OL[il * 72 + d0 + c];
    size_t base = ((size_t)(bh >> 4) * 1024 + q0 + il) * 1024 + (bh & 15) * 64 + d0;
    *(uint4*)&Ctx[base] = pkk.u[0];
    *(uint4*)&Ctx[base + 8] = pkk.u[1];
  }
}

// ---------------- launch ----------------
extern "C" void kernel_launch(void* const* d_in, const int* in_sizes, int n_in,
                              void* d_out, int out_size, void* d_ws, size_t ws_size,
                              hipStream_t stream) {
  const float* x = (const float*)d_in[0];
  const float* Wq = (const float*)d_in[1];
  const float* Wk = (const float*)d_in[2];
  const float* Wv = (const float*)d_in[3];
  const float* Wo = (const float*)d_in[4];
  const float* bo = (const float*)d_in[5];
  const float* relk = (const float*)d_in[6];
  const float* relv = (const float*)d_in[7];
  float* out = (float*)d_out;

  uint8_t* w = (uint8_t*)d_ws;
  bf16* xb = (bf16*)(w);                          // 16 MB  [8192][1024]
  bf16* Wb = (bf16*)(w + 16777216);               // 8 MB   [4][1024][1024]
  bf16* Qb = (bf16*)(w + 25165824);               // 16 MB  [bh][s][64]
  bf16* Kb = (bf16*)(w + 41943040);               // 16 MB
  bf16* Vb = (bf16*)(w + 58720256);               // 16 MB
  bf16* Vt = (bf16*)(w + 75497472);               // 16 MB  [bh][64][s]
  bf16* Qrel = (bf16*)(w + 92274688);             // 21 MB  [bh*s][80]
  bf16* Ctx = Vb;                                 // overlay (Vb dead after transpose)
  bf16* RVt = xb;                                 // overlay (xb dead after qkv gemm)

  k_cvtall<<<12288, 256, 0, stream>>>(x, Wq, Wk, Wv, Wo, xb, Wb);

  dim3 gg(64, 8, 3);
  k_gemm_qkv<<<gg, 256, 0, stream>>>(xb, Wb, Qb, Kb, Vb);
  k_transpose<<<dim3(16, 128), 256, 0, stream>>>(Vb, Vt);
  k_qrel<<<2072, 256, 0, stream>>>(Qb, relk, Qrel, relv, RVt);
  k_attn<<<2048, 256, 0, stream>>>(Qb, Kb, Vt, Qrel, RVt, relv, Ctx);
  k_gemm_out<<<dim3(64, 8), 256, 0, stream>>>(Ctx, Wb + 3 * 1048576, bo, out);
}